// Round 9
// baseline (7518.000 us; speedup 1.0000x reference)
//
#include <hip/hip_runtime.h>

// 2-layer GRU, B=512 T=2048 IN=16 H=128 OUT=8.
// 32 WGs x 512 threads (8 waves, 2/SIMD). Wave w owns hidden cols [16w,16w+16).
// Champion (r2, 3056us) structure: A=h/x (rows=batch), B=weights (cols=hidden),
// achunk-permuted LDS (0 bank conflicts), __syncthreads barriers, splat biases.
// NEW: hh1 MFMAs (on h1(t-1)) + wave-7 out-proj MFMAs folded into PHASE A so
// their MFMA-pipe time overlaps phase-A's elementwise trans chain (separate
// pipes, same wave -> no sync needed). Phase B = ih1 MFMAs + elem1 only.

typedef unsigned int  uint;
typedef unsigned short ushort;
typedef _Float16 v8h __attribute__((ext_vector_type(8)));
typedef float    v4f __attribute__((ext_vector_type(4)));

#define Tq   2048
#define INq  16
#define Hq   128
#define OUTq 8
#define BW   16

#define MFMA(a,b,c) __builtin_amdgcn_mfma_f32_16x16x32_f16((a),(b),(c),0,0,0)

__device__ __forceinline__ float sigm(float x){
  return __builtin_amdgcn_rcpf(1.0f + __expf(-x));
}
__device__ __forceinline__ float tanh_f(float x){
  return 1.0f - 2.0f*__builtin_amdgcn_rcpf(__expf(2.0f*x) + 1.0f);
}
__device__ __forceinline__ uint packh2(float lo, float hi){
  _Float16 a=(_Float16)lo, b=(_Float16)hi;
  return (uint)__builtin_bit_cast(ushort,a) | ((uint)__builtin_bit_cast(ushort,b)<<16);
}
__device__ __forceinline__ int achunk(int row, int kq){
  return row*4 + (kq ^ ((row>>1)&3));   // conflict-free A-frag swizzle (r2)
}

__global__ __launch_bounds__(512,2) void gru2_kernel(
    const float* __restrict__ x,
    const float* __restrict__ Wih0, const float* __restrict__ Whh0,
    const float* __restrict__ bih0, const float* __restrict__ bhh0,
    const float* __restrict__ Wih1, const float* __restrict__ Whh1,
    const float* __restrict__ bih1, const float* __restrict__ bhh1,
    const float* __restrict__ Wout, const float* __restrict__ bout,
    float* __restrict__ out)
{
  const int tid  = threadIdx.x;
  const int lane = tid & 63;
  const int w    = tid >> 6;      // wave 0..7: hidden slice [16w,16w+16)
  const int col  = lane & 15;     // MFMA col (hidden / out-dim); A row (batch)
  const int bg   = lane >> 4;     // k-group for frags; batch-group for C/D
  const int b0   = blockIdx.x * BW;
  const int hb   = 16*w + col;    // hidden index this lane owns (B-operand)

  // x(0) prefetch issued ASAP, hides under weight prologue
  const float* xrow = &x[(size_t)(b0+col)*Tq*INq];
  float4 xfa, xfb;
  if (bg < 2){
    xfa = *(const float4*)&xrow[0*INq + bg*8 + 0];
    xfb = *(const float4*)&xrow[0*INq + bg*8 + 4];
  }

  __shared__ __align__(16) _Float16 hA0[2][2048];  // [buf][ks*512+chunk*8+e]
  __shared__ __align__(16) _Float16 hA1[2][2048];

  for (int i = tid; i < 2048; i += 512){ ((uint*)hA0)[i]=0u; ((uint*)hA1)[i]=0u; }

  // ---------------- weight fragments (registers, f16) ----------------
  v8h Fhh0[3][4], Fih1[3][4], Fhh1[3][4], Fx[3], Fo[4];
  #pragma unroll
  for (int g=0; g<3; ++g){
    const int r = g*Hq + hb;
    #pragma unroll
    for (int ks=0; ks<4; ++ks){
      const float* p0 = &Whh0[r*Hq + ks*32 + bg*8];
      const float* p1 = &Wih1[r*Hq + ks*32 + bg*8];
      const float* p2 = &Whh1[r*Hq + ks*32 + bg*8];
      v8h a, b, c;
      #pragma unroll
      for (int e=0;e<8;++e){ a[e]=(_Float16)p0[e]; b[e]=(_Float16)p1[e]; c[e]=(_Float16)p2[e]; }
      Fhh0[g][ks]=a; Fih1[g][ks]=b; Fhh1[g][ks]=c;
    }
    v8h vx;
    #pragma unroll
    for (int e=0;e<8;++e) vx[e]=(_Float16)0.f;
    if (bg < 2){
      const float* p = &Wih0[r*INq + bg*8];
      #pragma unroll
      for (int e=0;e<8;++e) vx[e]=(_Float16)p[e];
    }
    Fx[g]=vx;
  }
  #pragma unroll
  for (int ks=0; ks<4; ++ks){
    v8h v;
    #pragma unroll
    for (int e=0;e<8;++e) v[e]=(_Float16)0.f;
    if (col < OUTq){
      const float* p = &Wout[col*Hq + ks*32 + bg*8];
      #pragma unroll
      for (int e=0;e<8;++e) v[e]=(_Float16)p[e];
    }
    Fo[ks]=v;
  }
  const float bo_s  = (col<OUTq) ? bout[col] : 0.f;
  const float bs_r  = bih0[hb]      + bhh0[hb];
  const float bs_z  = bih0[Hq+hb]   + bhh0[Hq+hb];
  const float bs_nx = bih0[2*Hq+hb];
  const float bs_nh = bhh0[2*Hq+hb];
  const float c1_r  = bih1[hb]      + bhh1[hb];
  const float c1_z  = bih1[Hq+hb]   + bhh1[Hq+hb];
  const float c1_nx = bih1[2*Hq+hb];
  const float c1_nh = bhh1[2*Hq+hb];

  float h0s[4] = {0,0,0,0};          // persistent h-state, C/D layout
  float h1s[4] = {0,0,0,0};

  const int rch    = achunk(col, bg);   // read chunk (row=col(batch), kq=bg)
  const int wtile  = hb >> 5;           // write base for own h column
  const int kq_w   = (hb >> 3) & 3;
  const int elem_w = hb & 7;

  __syncthreads();

  for (int t=0; t<Tq; ++t){
    const int cur = t & 1, prv = cur ^ 1;

    // ======== PHASE A: L0 gates + (hh1 + out) on h1(t-1) ========
    // reads: a0k = h0(t-1), a1k = h1(t-1)
    v8h a0k[4], a1k[4];
    #pragma unroll
    for (int ks=0; ks<4; ++ks){
      a0k[ks] = *(const v8h*)&hA0[prv][ks*512 + rch*8];
      a1k[ks] = *(const v8h*)&hA1[prv][ks*512 + rch*8];
    }

    // x(t) -> f16 A-frag, prefetch x(t+1)
    v8h ax;
    #pragma unroll
    for (int e=0;e<8;++e) ax[e]=(_Float16)0.f;
    if (bg < 2){
      ax[0]=(_Float16)xfa.x; ax[1]=(_Float16)xfa.y; ax[2]=(_Float16)xfa.z; ax[3]=(_Float16)xfa.w;
      ax[4]=(_Float16)xfb.x; ax[5]=(_Float16)xfb.y; ax[6]=(_Float16)xfb.z; ax[7]=(_Float16)xfb.w;
      int tn = t+1; if (tn > Tq-1) tn = Tq-1;
      xfa = *(const float4*)&xrow[tn*INq + bg*8 + 0];
      xfb = *(const float4*)&xrow[tn*INq + bg*8 + 4];
    }

    // L0 gate accumulators
    v4f aR  = {bs_r, bs_r, bs_r, bs_r};
    v4f aZ  = {bs_z, bs_z, bs_z, bs_z};
    v4f aNX = {bs_nx,bs_nx,bs_nx,bs_nx};
    v4f aNH = {bs_nh,bs_nh,bs_nh,bs_nh};
    aR  = MFMA(ax, Fx[0], aR);
    aZ  = MFMA(ax, Fx[1], aZ);
    aNX = MFMA(ax, Fx[2], aNX);
    #pragma unroll
    for (int ks=0; ks<4; ++ks){
      aR  = MFMA(a0k[ks], Fhh0[0][ks], aR);
      aZ  = MFMA(a0k[ks], Fhh0[1][ks], aZ);
      aNH = MFMA(a0k[ks], Fhh0[2][ks], aNH);
    }
    // hh1 on h1(t-1): persistent accumulators, finished in phase B
    v4f cR  = {c1_r, c1_r, c1_r, c1_r};
    v4f cZ  = {c1_z, c1_z, c1_z, c1_z};
    v4f cNH = {c1_nh,c1_nh,c1_nh,c1_nh};
    #pragma unroll
    for (int ks=0; ks<4; ++ks){
      cR  = MFMA(a1k[ks], Fhh1[0][ks], cR);
      cZ  = MFMA(a1k[ks], Fhh1[1][ks], cZ);
      cNH = MFMA(a1k[ks], Fhh1[2][ks], cNH);
    }
    // out(t-1) = Wout @ h1(t-1) on wave 7 (a1k already in regs)
    v4f oac = {0.f,0.f,0.f,0.f};
    if (w == 7){
      #pragma unroll
      for (int ks=0; ks<4; ++ks) oac = MFMA(a1k[ks], Fo[ks], oac);
    }
    // elem-0 (trans chain overlaps the hh1/out MFMA pipe tail)
    float hn0[4];
    #pragma unroll
    for (int j=0;j<4;++j){
      float r = sigm(aR[j]);
      float z = sigm(aZ[j]);
      float n = tanh_f(aNX[j] + r*aNH[j]);
      float h = n + z*(h0s[j]-n);
      h0s[j]=h; hn0[j]=h;
    }
    #pragma unroll
    for (int j=0;j<4;++j)
      hA0[cur][wtile*512 + achunk(bg*4+j, kq_w)*8 + elem_w] = (_Float16)hn0[j];
    __syncthreads();                                   // barrier 1

    // ======== PHASE B: ih1 on h0(t) + elem-1 ========
    if (w == 7 && t > 0 && col < OUTq){                // store out(t-1)
      #pragma unroll
      for (int j=0;j<4;++j)
        out[(size_t)((b0 + bg*4 + j)*Tq + (t-1))*OUTq + col] = oac[j] + bo_s;
    }
    v4f cNX = {c1_nx,c1_nx,c1_nx,c1_nx};
    #pragma unroll
    for (int ks=0; ks<4; ++ks){
      v8h a0n = *(const v8h*)&hA0[cur][ks*512 + rch*8];
      cR  = MFMA(a0n, Fih1[0][ks], cR);
      cZ  = MFMA(a0n, Fih1[1][ks], cZ);
      cNX = MFMA(a0n, Fih1[2][ks], cNX);
    }
    float hn1[4];
    #pragma unroll
    for (int j=0;j<4;++j){
      float r = sigm(cR[j]);
      float z = sigm(cZ[j]);
      float n = tanh_f(cNX[j] + r*cNH[j]);
      float h = n + z*(h1s[j]-n);
      h1s[j]=h; hn1[j]=h;
    }
    #pragma unroll
    for (int j=0;j<4;++j)
      hA1[cur][wtile*512 + achunk(bg*4+j, kq_w)*8 + elem_w] = (_Float16)hn1[j];
    __syncthreads();                                   // barrier 2
  }

  // epilogue: out(Tq-1) from h1(Tq-1) in hA1[(Tq-1)&1 == 1]
  if (w == 7){
    v4f oac = {0.f,0.f,0.f,0.f};
    #pragma unroll
    for (int ks=0; ks<4; ++ks){
      v8h a1 = *(const v8h*)&hA1[1][ks*512 + rch*8];
      oac = MFMA(a1, Fo[ks], oac);
    }
    if (col < OUTq){
      #pragma unroll
      for (int j=0;j<4;++j)
        out[(size_t)((b0 + bg*4 + j)*Tq + (Tq-1))*OUTq + col] = oac[j] + bo_s;
    }
  }
}

extern "C" void kernel_launch(void* const* d_in, const int* in_sizes, int n_in,
                              void* d_out, int out_size, void* d_ws, size_t ws_size,
                              hipStream_t stream) {
  const float* x    = (const float*)d_in[0];
  const float* Wih0 = (const float*)d_in[1];
  const float* Whh0 = (const float*)d_in[2];
  const float* bih0 = (const float*)d_in[3];
  const float* bhh0 = (const float*)d_in[4];
  const float* Wih1 = (const float*)d_in[5];
  const float* Whh1 = (const float*)d_in[6];
  const float* bih1 = (const float*)d_in[7];
  const float* bhh1 = (const float*)d_in[8];
  const float* Wout = (const float*)d_in[9];
  const float* bo   = (const float*)d_in[10];
  gru2_kernel<<<dim3(32), dim3(512), 0, stream>>>(
      x, Wih0, Whh0, bih0, bhh0, Wih1, Whh1, bih1, bhh1, Wout, bo,
      (float*)d_out);
}

// Round 10
// 5141.351 us; speedup vs baseline: 1.4623x; 1.4623x over previous
//
#include <hip/hip_runtime.h>

// 2-layer GRU, B=512 T=2048 IN=16 H=128 OUT=8.
// 32 WGs x 512 threads (8 waves, 2/SIMD). Wave w owns hidden cols [16w,16w+16).
// Champion (r2, 3056us) base: A=h/x (rows=batch), B=weights, achunk LDS
// swizzle (0 conflicts), __syncthreads, splat biases, scalar b16 h-writes.
// NEW (register-lean half-tick shift): L1 gate pre-acts (cR/cZ/cNX/cNH,
// 16 regs) stay live across the barrier; e1(t-1) runs INSIDE phase 1 where
// it is independent of L0's MFMAs -> trans pipe overlaps MFMA pipe.
// Phase 2 = pure L1 MFMAs (+ wave-7 out-proj, Wout frags in LDS to keep
// register peak at champion level). Single h1 LDS buffer (hazard-checked).

typedef unsigned int  uint;
typedef unsigned short ushort;
typedef _Float16 v8h __attribute__((ext_vector_type(8)));
typedef float    v4f __attribute__((ext_vector_type(4)));

#define Tq   2048
#define INq  16
#define Hq   128
#define OUTq 8
#define BW   16

#define MFMA(a,b,c) __builtin_amdgcn_mfma_f32_16x16x32_f16((a),(b),(c),0,0,0)

__device__ __forceinline__ float sigm(float x){
  return __builtin_amdgcn_rcpf(1.0f + __expf(-x));
}
__device__ __forceinline__ float tanh_f(float x){
  return 1.0f - 2.0f*__builtin_amdgcn_rcpf(__expf(2.0f*x) + 1.0f);
}
__device__ __forceinline__ int achunk(int row, int kq){
  return row*4 + (kq ^ ((row>>1)&3));   // conflict-free A-frag swizzle
}

__global__ __launch_bounds__(512,2) void gru2_kernel(
    const float* __restrict__ x,
    const float* __restrict__ Wih0, const float* __restrict__ Whh0,
    const float* __restrict__ bih0, const float* __restrict__ bhh0,
    const float* __restrict__ Wih1, const float* __restrict__ Whh1,
    const float* __restrict__ bih1, const float* __restrict__ bhh1,
    const float* __restrict__ Wout, const float* __restrict__ bout,
    float* __restrict__ out)
{
  const int tid  = threadIdx.x;
  const int lane = tid & 63;
  const int w    = tid >> 6;      // wave 0..7: hidden slice [16w,16w+16)
  const int col  = lane & 15;     // MFMA col (hidden/out); A row (batch)
  const int bg   = lane >> 4;     // k-group; batch-group for C/D
  const int b0   = blockIdx.x * BW;
  const int hb   = 16*w + col;    // hidden index this lane owns (B-operand)

  // x(0) prefetch ASAP (hides under weight prologue)
  const float* xrow = &x[(size_t)(b0+col)*Tq*INq];
  float4 xfa, xfb;
  if (bg < 2){
    xfa = *(const float4*)&xrow[0*INq + bg*8 + 0];
    xfb = *(const float4*)&xrow[0*INq + bg*8 + 4];
  }

  __shared__ __align__(16) _Float16 hA0[2][2048];  // [buf][ks*512+chunk*8+e]
  __shared__ __align__(16) _Float16 hA1[2048];     // single buffer (h1(t-1))
  __shared__ __align__(16) _Float16 w3l[2048];     // Wout frags [ks][lane][8]

  for (int i = tid; i < 2048; i += 512) ((uint*)hA0)[i]=0u;
  for (int i = tid; i < 1024; i += 512) ((uint*)hA1)[i]=0u;

  // ---------------- weight fragments (registers, f16) ----------------
  v8h Fhh0[3][4], Fih1[3][4], Fhh1[3][4], Fx[3];
  #pragma unroll
  for (int g=0; g<3; ++g){
    const int r = g*Hq + hb;
    #pragma unroll
    for (int ks=0; ks<4; ++ks){
      const float* p0 = &Whh0[r*Hq + ks*32 + bg*8];
      const float* p1 = &Wih1[r*Hq + ks*32 + bg*8];
      const float* p2 = &Whh1[r*Hq + ks*32 + bg*8];
      v8h a, b, c;
      #pragma unroll
      for (int e=0;e<8;++e){ a[e]=(_Float16)p0[e]; b[e]=(_Float16)p1[e]; c[e]=(_Float16)p2[e]; }
      Fhh0[g][ks]=a; Fih1[g][ks]=b; Fhh1[g][ks]=c;
    }
    v8h vx;
    #pragma unroll
    for (int e=0;e<8;++e) vx[e]=(_Float16)0.f;
    if (bg < 2){
      const float* p = &Wih0[r*INq + bg*8];
      #pragma unroll
      for (int e=0;e<8;++e) vx[e]=(_Float16)p[e];
    }
    Fx[g]=vx;
  }
  if (w == 7){                    // Wout frags -> LDS (saves 16 regs/lane)
    #pragma unroll
    for (int ks=0; ks<4; ++ks){
      v8h v;
      #pragma unroll
      for (int e=0;e<8;++e) v[e]=(_Float16)0.f;
      if (col < OUTq){
        const float* p = &Wout[col*Hq + ks*32 + bg*8];
        #pragma unroll
        for (int e=0;e<8;++e) v[e]=(_Float16)p[e];
      }
      *(v8h*)&w3l[ks*512 + lane*8] = v;
    }
  }
  const float bo_s  = (col<OUTq) ? bout[col] : 0.f;
  const float bs_r  = bih0[hb]      + bhh0[hb];
  const float bs_z  = bih0[Hq+hb]   + bhh0[Hq+hb];
  const float bs_nx = bih0[2*Hq+hb];
  const float bs_nh = bhh0[2*Hq+hb];
  const float c1_r  = bih1[hb]      + bhh1[hb];
  const float c1_z  = bih1[Hq+hb]   + bhh1[Hq+hb];
  const float c1_nx = bih1[2*Hq+hb];
  const float c1_nh = bhh1[2*Hq+hb];

  float h0s[4] = {0,0,0,0};          // persistent h-state, C/D layout
  float h1s[4] = {0,0,0,0};
  v4f cR, cZ, cNX, cNH;              // L1 pre-acts, live ph2(t) -> ph1(t+1)

  const int rch    = achunk(col, bg);
  const int wtile  = hb >> 5;
  const int kq_w   = (hb >> 3) & 3;
  const int elem_w = hb & 7;
  const int wbase  = wtile*512 + elem_w;

  __syncthreads();

  for (int t=0; t<Tq; ++t){
    const int cur = t & 1, prv = cur ^ 1;

    // ======== PHASE 1: L0-MFMA(t)  ||  e1(t-1)  -> e0(t) ========
    v8h a0k[4];
    #pragma unroll
    for (int ks=0; ks<4; ++ks) a0k[ks] = *(const v8h*)&hA0[prv][ks*512 + rch*8];

    v8h ax;
    #pragma unroll
    for (int e=0;e<8;++e) ax[e]=(_Float16)0.f;
    if (bg < 2){
      ax[0]=(_Float16)xfa.x; ax[1]=(_Float16)xfa.y; ax[2]=(_Float16)xfa.z; ax[3]=(_Float16)xfa.w;
      ax[4]=(_Float16)xfb.x; ax[5]=(_Float16)xfb.y; ax[6]=(_Float16)xfb.z; ax[7]=(_Float16)xfb.w;
      int tn = t+1; if (tn > Tq-1) tn = Tq-1;
      xfa = *(const float4*)&xrow[tn*INq + bg*8 + 0];
      xfb = *(const float4*)&xrow[tn*INq + bg*8 + 4];
    }

    v4f aR  = {bs_r, bs_r, bs_r, bs_r};
    v4f aZ  = {bs_z, bs_z, bs_z, bs_z};
    v4f aNX = {bs_nx,bs_nx,bs_nx,bs_nx};
    v4f aNH = {bs_nh,bs_nh,bs_nh,bs_nh};
    aR  = MFMA(ax, Fx[0], aR);
    aZ  = MFMA(ax, Fx[1], aZ);
    aNX = MFMA(ax, Fx[2], aNX);
    #pragma unroll
    for (int ks=0; ks<4; ++ks){
      aR  = MFMA(a0k[ks], Fhh0[0][ks], aR);
      aZ  = MFMA(a0k[ks], Fhh0[1][ks], aZ);
      aNH = MFMA(a0k[ks], Fhh0[2][ks], aNH);
    }

    // e1(t-1): independent of the MFMAs above -> trans overlaps MFMA pipe
    if (t > 0){
      float hn1[4];
      #pragma unroll
      for (int j=0;j<4;++j){
        float r = sigm(cR[j]);
        float z = sigm(cZ[j]);
        float n = tanh_f(cNX[j] + r*cNH[j]);
        float h = n + z*(h1s[j]-n);
        h1s[j]=h; hn1[j]=h;
      }
      #pragma unroll
      for (int j=0;j<4;++j)
        hA1[wbase + achunk(bg*4+j, kq_w)*8] = (_Float16)hn1[j];
    }

    // e0(t): depends on L0-MFMA results
    float hn0[4];
    #pragma unroll
    for (int j=0;j<4;++j){
      float r = sigm(aR[j]);
      float z = sigm(aZ[j]);
      float n = tanh_f(aNX[j] + r*aNH[j]);
      float h = n + z*(h0s[j]-n);
      h0s[j]=h; hn0[j]=h;
    }
    #pragma unroll
    for (int j=0;j<4;++j)
      hA0[cur][wbase + achunk(bg*4+j, kq_w)*8] = (_Float16)hn0[j];
    __syncthreads();                                   // barrier 1

    // ======== PHASE 2: pure L1-MFMA(t) (+ wave-7 out(t-1)) ========
    cR = (v4f){c1_r, c1_r, c1_r, c1_r};
    cZ = (v4f){c1_z, c1_z, c1_z, c1_z};
    cNX= (v4f){c1_nx,c1_nx,c1_nx,c1_nx};
    cNH= (v4f){c1_nh,c1_nh,c1_nh,c1_nh};
    v4f oac = {0.f,0.f,0.f,0.f};
    #pragma unroll
    for (int ks=0; ks<4; ++ks){
      v8h a0n = *(const v8h*)&hA0[cur][ks*512 + rch*8];
      v8h a1  = *(const v8h*)&hA1[ks*512 + rch*8];
      cR  = MFMA(a0n, Fih1[0][ks], cR);
      cZ  = MFMA(a0n, Fih1[1][ks], cZ);
      cNX = MFMA(a0n, Fih1[2][ks], cNX);
      cR  = MFMA(a1,  Fhh1[0][ks], cR);
      cZ  = MFMA(a1,  Fhh1[1][ks], cZ);
      cNH = MFMA(a1,  Fhh1[2][ks], cNH);
      if (w == 7){
        v8h wf = *(const v8h*)&w3l[ks*512 + lane*8];
        oac = MFMA(a1, wf, oac);
      }
    }
    if (w == 7 && t >= 1 && col < OUTq){               // out(t-1)
      #pragma unroll
      for (int j=0;j<4;++j)
        out[(size_t)((b0 + bg*4 + j)*Tq + (t-1))*OUTq + col] = oac[j] + bo_s;
    }
    __syncthreads();                                   // barrier 2
  }

  // ===== epilogue: e1(Tq-1) -> hA1, then out(Tq-1) =====
  {
    float hn1[4];
    #pragma unroll
    for (int j=0;j<4;++j){
      float r = sigm(cR[j]);
      float z = sigm(cZ[j]);
      float n = tanh_f(cNX[j] + r*cNH[j]);
      float h = n + z*(h1s[j]-n);
      hn1[j]=h;
    }
    #pragma unroll
    for (int j=0;j<4;++j)
      hA1[wbase + achunk(bg*4+j, kq_w)*8] = (_Float16)hn1[j];
  }
  __syncthreads();
  if (w == 7){
    v4f oac = {0.f,0.f,0.f,0.f};
    #pragma unroll
    for (int ks=0; ks<4; ++ks){
      v8h a1 = *(const v8h*)&hA1[ks*512 + rch*8];
      v8h wf = *(const v8h*)&w3l[ks*512 + lane*8];
      oac = MFMA(a1, wf, oac);
    }
    if (col < OUTq){
      #pragma unroll
      for (int j=0;j<4;++j)
        out[(size_t)((b0 + bg*4 + j)*Tq + (Tq-1))*OUTq + col] = oac[j] + bo_s;
    }
  }
}

extern "C" void kernel_launch(void* const* d_in, const int* in_sizes, int n_in,
                              void* d_out, int out_size, void* d_ws, size_t ws_size,
                              hipStream_t stream) {
  const float* x    = (const float*)d_in[0];
  const float* Wih0 = (const float*)d_in[1];
  const float* Whh0 = (const float*)d_in[2];
  const float* bih0 = (const float*)d_in[3];
  const float* bhh0 = (const float*)d_in[4];
  const float* Wih1 = (const float*)d_in[5];
  const float* Whh1 = (const float*)d_in[6];
  const float* bih1 = (const float*)d_in[7];
  const float* bhh1 = (const float*)d_in[8];
  const float* Wout = (const float*)d_in[9];
  const float* bo   = (const float*)d_in[10];
  gru2_kernel<<<dim3(32), dim3(512), 0, stream>>>(
      x, Wih0, Whh0, bih0, bhh0, Wih1, Whh1, bih1, bhh1, Wout, bo,
      (float*)d_out);
}